// Round 4
// baseline (235.358 us; speedup 1.0000x reference)
//
#include <hip/hip_runtime.h>

// Sparsemax along dim=-1 for [8192, 4096] fp32.
//
// Newton on f(tau) = sum_i max(0, x_i - tau) = 1, starting tau0 = max(x) - 1.
// Monotone, exact on support-set stabilization (~5-8 iters for Gaussian rows).
// One 64-lane wave per row; row held in registers (16 x float4 / lane).
//
// Round-2 lesson: VGPR_Count=48 -> compiler rematerialized row loads inside
// the Newton loop (L2 re-read every iteration, 85 us).
// Round-3 lesson: the asm "+v" pin alone didn't fix it -- VGPR stayed 48, so
// the compiler SPILLED to scratch instead (same L2 round-trip, same 85 us).
// The register BUDGET was the constraint: default launch_bounds targets high
// occupancy (VGPR<=64). __launch_bounds__(256, 1) lifts the budget to 512
// VGPR/wave; ~100 VGPR still gives ~5 waves/SIMD, plenty for streaming BW.

#define COLS 4096
#define WAVES_PER_BLOCK 4
#define MAX_NEWTON_ITERS 16

__global__ __launch_bounds__(256, 1) void sparsemax_kernel(
    const float* __restrict__ x, float* __restrict__ out, int rows) {
  const int lane = threadIdx.x & 63;
  const int wid = threadIdx.x >> 6;
  const long row = (long)blockIdx.x * WAVES_PER_BLOCK + wid;
  if (row >= rows) return;

  const float4* __restrict__ xr =
      reinterpret_cast<const float4*>(x + row * COLS);
  float4* __restrict__ outr = reinterpret_cast<float4*>(out + row * COLS);

  // Load full row: lane i takes float4 slots {i, i+64, ..., i+960} -> each
  // load instruction is 64 lanes x 16 B contiguous = 1 KiB coalesced.
  float4 v[16];
#pragma unroll
  for (int j = 0; j < 16; ++j) v[j] = xr[lane + j * 64];

  // Pin the row in VGPRs: the asm claims it may modify the values, so the
  // compiler cannot re-load them from memory later. Zero runtime cost when
  // the values are register-resident.
#pragma unroll
  for (int j = 0; j < 16; ++j) {
    asm volatile("" : "+v"(v[j].x), "+v"(v[j].y), "+v"(v[j].z), "+v"(v[j].w));
  }

  // Row max (per-lane tree, then butterfly across the wave).
  float m = fmaxf(fmaxf(v[0].x, v[0].y), fmaxf(v[0].z, v[0].w));
#pragma unroll
  for (int j = 1; j < 16; ++j) {
    m = fmaxf(m, fmaxf(fmaxf(v[j].x, v[j].y), fmaxf(v[j].z, v[j].w)));
  }
#pragma unroll
  for (int off = 32; off > 0; off >>= 1) m = fmaxf(m, __shfl_xor(m, off));

  float tau = m - 1.0f;

  for (int it = 0; it < MAX_NEWTON_ITERS; ++it) {
    float s = 0.0f;  // sum of x_i over support
    int c = 0;       // support count
#pragma unroll
    for (int j = 0; j < 16; ++j) {
      s += (v[j].x > tau) ? v[j].x : 0.0f;
      c += (v[j].x > tau) ? 1 : 0;
      s += (v[j].y > tau) ? v[j].y : 0.0f;
      c += (v[j].y > tau) ? 1 : 0;
      s += (v[j].z > tau) ? v[j].z : 0.0f;
      c += (v[j].z > tau) ? 1 : 0;
      s += (v[j].w > tau) ? v[j].w : 0.0f;
      c += (v[j].w > tau) ? 1 : 0;
    }
#pragma unroll
    for (int off = 32; off > 0; off >>= 1) {
      s += __shfl_xor(s, off);
      c += __shfl_xor(c, off);
    }
    // c >= 1 always: tau < tau* <= max(x), so the max element is in support.
    float ntau = (s - 1.0f) / (float)c;
    if (ntau == tau) break;  // wave-uniform: tau identical on all 64 lanes
    tau = ntau;
  }

  // Emit max(0, x - tau), coalesced float4 stores from the register copy.
#pragma unroll
  for (int j = 0; j < 16; ++j) {
    float4 o;
    o.x = fmaxf(v[j].x - tau, 0.0f);
    o.y = fmaxf(v[j].y - tau, 0.0f);
    o.z = fmaxf(v[j].z - tau, 0.0f);
    o.w = fmaxf(v[j].w - tau, 0.0f);
    outr[lane + j * 64] = o;
  }
}

extern "C" void kernel_launch(void* const* d_in, const int* in_sizes, int n_in,
                              void* d_out, int out_size, void* d_ws,
                              size_t ws_size, hipStream_t stream) {
  const float* x = (const float*)d_in[0];
  float* out = (float*)d_out;
  const int rows = in_sizes[0] / COLS;  // 8192
  const int blocks = (rows + WAVES_PER_BLOCK - 1) / WAVES_PER_BLOCK;  // 2048
  sparsemax_kernel<<<blocks, 256, 0, stream>>>(x, out, rows);
}

// Round 6
// 232.561 us; speedup vs baseline: 1.0120x; 1.0120x over previous
//
#include <hip/hip_runtime.h>

// Sparsemax along dim=-1 for [8192, 4096] fp32.
//
// Newton on f(tau) = sum_i max(0, x_i - tau) = 1, tau0 = max(x) - 1.
// Monotone from below, exact when the support set stabilizes.
//
// Rounds 2-4 lesson: the compiler refuses to keep the 64-float/lane row in
// VGPRs (VGPR_Count pinned at 48 under every launch_bounds / asm-pin
// combination) -> every Newton iteration re-read the row from L2/LLC, 85 us.
// Fix: make residency EXPLICIT.
//  (a) Row lives in LDS (16 KiB/row, 4 rows/block = 64 KiB) -- guaranteed.
//  (b) Candidate compaction: support subset of {x > max-1} (~14/4096 for
//      Gaussian rows). One LDS pass appends candidates via LDS atomicAdd;
//      Newton then runs over <=64 values held per-lane with shfl reductions.
//      Math identical to full-row Newton: every iterate has tau >= max-1, so
//      non-candidates can never enter the sums. Fallback to full-row-from-LDS
//      Newton if candidates overflow (correct for adversarial inputs).
//
// Each wave owns one row and touches only its own LDS slices: no
// __syncthreads anywhere; DS-pipe program order within a wave suffices.

#define COLS 4096
#define WAVES_PER_BLOCK 4
#define CAND_CAP 960   // keeps total LDS <= 80 KiB -> 2 blocks/CU
#define MAX_ITERS 32

__global__ __launch_bounds__(256) void sparsemax_kernel(
    const float* __restrict__ x, float* __restrict__ out, int rows) {
  __shared__ __align__(16) float rowbuf[WAVES_PER_BLOCK][COLS];
  __shared__ __align__(16) float cand[WAVES_PER_BLOCK][CAND_CAP];
  __shared__ int cnt[WAVES_PER_BLOCK];

  const int lane = threadIdx.x & 63;
  const int wid = threadIdx.x >> 6;
  const long row = (long)blockIdx.x * WAVES_PER_BLOCK + wid;
  if (row >= rows) return;

  if (lane == 0) cnt[wid] = 0;

  const float4* __restrict__ xr =
      reinterpret_cast<const float4*>(x + row * COLS);
  float4* __restrict__ outr = reinterpret_cast<float4*>(out + row * COLS);
  float4* rb = reinterpret_cast<float4*>(rowbuf[wid]);

  // Stage row into LDS and compute the row max in the same pass.
  // Lane i handles float4 slots {i, i+64, ...}: 1 KiB coalesced per load,
  // stride-1 ds_write_b128 (conflict-free).
  float m = -INFINITY;
#pragma unroll
  for (int j = 0; j < 16; ++j) {
    float4 v = xr[lane + j * 64];
    rb[lane + j * 64] = v;
    m = fmaxf(m, fmaxf(fmaxf(v.x, v.y), fmaxf(v.z, v.w)));
  }
#pragma unroll
  for (int off = 32; off > 0; off >>= 1) m = fmaxf(m, __shfl_xor(m, off));

  const float thr = m - 1.0f;

  // Compact candidates (x > max-1) into a small LDS buffer.
#pragma unroll
  for (int j = 0; j < 16; ++j) {
    float4 v = rb[lane + j * 64];
    if (v.x > thr) { int p = atomicAdd(&cnt[wid], 1); if (p < CAND_CAP) cand[wid][p] = v.x; }
    if (v.y > thr) { int p = atomicAdd(&cnt[wid], 1); if (p < CAND_CAP) cand[wid][p] = v.y; }
    if (v.z > thr) { int p = atomicAdd(&cnt[wid], 1); if (p < CAND_CAP) cand[wid][p] = v.z; }
    if (v.w > thr) { int p = atomicAdd(&cnt[wid], 1); if (p < CAND_CAP) cand[wid][p] = v.w; }
  }

  const int nc = cnt[wid];  // DS ops in-order within the wave
  float tau = thr;

  if (nc <= CAND_CAP) {
    // Fast path: Newton over the (tiny) candidate set.
    for (int it = 0; it < MAX_ITERS; ++it) {
      float s = 0.0f;
      int c = 0;
      for (int k = lane; k < nc; k += 64) {
        float v = cand[wid][k];
        if (v > tau) { s += v; c += 1; }
      }
#pragma unroll
      for (int off = 32; off > 0; off >>= 1) {
        s += __shfl_xor(s, off);
        c += __shfl_xor(c, off);
      }
      float ntau = (s - 1.0f) / (float)c;  // c >= 1: max elem always in support
      if (ntau == tau) break;              // wave-uniform exact fixed point
      tau = ntau;
    }
  } else {
    // Fallback: full-row Newton from LDS (adversarial inputs only).
    for (int it = 0; it < MAX_ITERS; ++it) {
      float s = 0.0f;
      int c = 0;
#pragma unroll
      for (int j = 0; j < 16; ++j) {
        float4 v = rb[lane + j * 64];
        if (v.x > tau) { s += v.x; c += 1; }
        if (v.y > tau) { s += v.y; c += 1; }
        if (v.z > tau) { s += v.z; c += 1; }
        if (v.w > tau) { s += v.w; c += 1; }
      }
#pragma unroll
      for (int off = 32; off > 0; off >>= 1) {
        s += __shfl_xor(s, off);
        c += __shfl_xor(c, off);
      }
      float ntau = (s - 1.0f) / (float)c;
      if (ntau == tau) break;
      tau = ntau;
    }
  }

  // Output pass: read row back from LDS, emit max(0, x - tau).
#pragma unroll
  for (int j = 0; j < 16; ++j) {
    float4 v = rb[lane + j * 64];
    float4 o;
    o.x = fmaxf(v.x - tau, 0.0f);
    o.y = fmaxf(v.y - tau, 0.0f);
    o.z = fmaxf(v.z - tau, 0.0f);
    o.w = fmaxf(v.w - tau, 0.0f);
    outr[lane + j * 64] = o;
  }
}

extern "C" void kernel_launch(void* const* d_in, const int* in_sizes, int n_in,
                              void* d_out, int out_size, void* d_ws,
                              size_t ws_size, hipStream_t stream) {
  const float* x = (const float*)d_in[0];
  float* out = (float*)d_out;
  const int rows = in_sizes[0] / COLS;  // 8192
  const int blocks = (rows + WAVES_PER_BLOCK - 1) / WAVES_PER_BLOCK;  // 2048
  sparsemax_kernel<<<blocks, 256, 0, stream>>>(x, out, rows);
}

// Round 7
// 231.295 us; speedup vs baseline: 1.0176x; 1.0055x over previous
//
#include <hip/hip_runtime.h>

// Sparsemax along dim=-1 for [8192, 4096] fp32.
//
// Newton on f(tau) = sum_i max(0, x_i - tau) = 1, tau0 = max(x) - 1.
// Monotone from below; exact when the support set stabilizes.
//
// History: R2-R6 all used ONE WAVE per row (16 KiB/wave) and all landed at
// 85-88 us regardless of inner structure (remat / spill / LDS-resident /
// candidate compaction) with every pipe idle (VALU 9-23%, HBM 28%, occ 16-39%)
// -> latency-bound on the per-wave serial chain, not compute or BW.
// This round: 256 THREADS per row (8192 blocks). Per-thread data = 16 floats
// = 16 VGPRs (register residency is now trivially cheap -- the R2 remat fight
// was over 64 floats/lane). No LDS row buffer -> ~4.5 KB LDS -> full
// occupancy; per-row serial chain shrinks 4x. Output uses nontemporal stores
// (write-once data; keep it from evicting the input from L2/L3).

#define COLS 4096
#define THREADS 256
#define NW 4  // waves per block
#define CAND_CAP 1024
#define MAX_ITERS 32

typedef float f32x4 __attribute__((ext_vector_type(4)));

__global__ __launch_bounds__(THREADS) void sparsemax_kernel(
    const float* __restrict__ x, float* __restrict__ out) {
  __shared__ float cand[CAND_CAP];
  __shared__ float wmax[NW];
  __shared__ float wsum[NW];
  __shared__ int wcnt[NW];
  __shared__ int cnt;

  const int tid = threadIdx.x;
  const int lane = tid & 63;
  const int wid = tid >> 6;
  const long row = blockIdx.x;

  const f32x4* __restrict__ xr =
      reinterpret_cast<const f32x4*>(x + row * COLS);
  f32x4* __restrict__ outr = reinterpret_cast<f32x4*>(out + row * COLS);

  if (tid == 0) cnt = 0;

  // Thread t holds float4 slots {t, t+256, t+512, t+768}: each load
  // instruction is fully coalesced (64 lanes x 16 B contiguous per wave).
  f32x4 v0 = xr[tid];
  f32x4 v1 = xr[tid + THREADS];
  f32x4 v2 = xr[tid + 2 * THREADS];
  f32x4 v3 = xr[tid + 3 * THREADS];

  // Row max: per-thread tree -> wave butterfly -> cross-wave via LDS.
  float m = fmaxf(fmaxf(v0.x, v0.y), fmaxf(v0.z, v0.w));
  m = fmaxf(m, fmaxf(fmaxf(v1.x, v1.y), fmaxf(v1.z, v1.w)));
  m = fmaxf(m, fmaxf(fmaxf(v2.x, v2.y), fmaxf(v2.z, v2.w)));
  m = fmaxf(m, fmaxf(fmaxf(v3.x, v3.y), fmaxf(v3.z, v3.w)));
#pragma unroll
  for (int off = 32; off > 0; off >>= 1) m = fmaxf(m, __shfl_xor(m, off));
  if (lane == 0) wmax[wid] = m;
  __syncthreads();
  m = fmaxf(fmaxf(wmax[0], wmax[1]), fmaxf(wmax[2], wmax[3]));

  const float thr = m - 1.0f;

  // Compact candidates (x > max-1) into LDS. Support is a subset of the
  // candidate set for EVERY Newton iterate (tau >= max-1 always), so the
  // filtered sums are bit-identical to full-row sums. ~14/4096 for Gaussian.
#define EMIT(val)                                   \
  if ((val) > thr) {                                \
    int p = atomicAdd(&cnt, 1);                     \
    if (p < CAND_CAP) cand[p] = (val);              \
  }
  EMIT(v0.x) EMIT(v0.y) EMIT(v0.z) EMIT(v0.w)
  EMIT(v1.x) EMIT(v1.y) EMIT(v1.z) EMIT(v1.w)
  EMIT(v2.x) EMIT(v2.y) EMIT(v2.z) EMIT(v2.w)
  EMIT(v3.x) EMIT(v3.y) EMIT(v3.z) EMIT(v3.w)
#undef EMIT
  __syncthreads();
  const int nc = cnt;

  float tau = thr;
  if (nc <= CAND_CAP) {
    // Fast path: each wave redundantly solves over the tiny candidate set
    // (identical results; no barriers inside the loop).
    for (int it = 0; it < MAX_ITERS; ++it) {
      float s = 0.0f;
      int c = 0;
      for (int k = lane; k < nc; k += 64) {
        float q = cand[k];
        if (q > tau) { s += q; c += 1; }
      }
#pragma unroll
      for (int off = 32; off > 0; off >>= 1) {
        s += __shfl_xor(s, off);
        c += __shfl_xor(c, off);
      }
      float ntau = (s - 1.0f) / (float)c;  // c >= 1: max elem in support
      if (ntau == tau) break;              // wave-uniform exact fixed point
      tau = ntau;
    }
  } else {
    // Fallback (adversarial inputs): block-wide Newton over register data.
    for (int it = 0; it < MAX_ITERS; ++it) {
      float s = 0.0f;
      int c = 0;
#define ACC(val)                      \
  if ((val) > tau) { s += (val); c += 1; }
      ACC(v0.x) ACC(v0.y) ACC(v0.z) ACC(v0.w)
      ACC(v1.x) ACC(v1.y) ACC(v1.z) ACC(v1.w)
      ACC(v2.x) ACC(v2.y) ACC(v2.z) ACC(v2.w)
      ACC(v3.x) ACC(v3.y) ACC(v3.z) ACC(v3.w)
#undef ACC
#pragma unroll
      for (int off = 32; off > 0; off >>= 1) {
        s += __shfl_xor(s, off);
        c += __shfl_xor(c, off);
      }
      if (lane == 0) { wsum[wid] = s; wcnt[wid] = c; }
      __syncthreads();
      s = wsum[0] + wsum[1] + wsum[2] + wsum[3];
      c = wcnt[0] + wcnt[1] + wcnt[2] + wcnt[3];
      float ntau = (s - 1.0f) / (float)c;
      __syncthreads();  // protect wsum/wcnt reuse next iteration
      if (ntau == tau) break;  // block-uniform: all threads break together
      tau = ntau;
    }
  }

  // Output from registers; nontemporal (write-once, never re-read).
  f32x4 o;
  o.x = fmaxf(v0.x - tau, 0.0f); o.y = fmaxf(v0.y - tau, 0.0f);
  o.z = fmaxf(v0.z - tau, 0.0f); o.w = fmaxf(v0.w - tau, 0.0f);
  __builtin_nontemporal_store(o, outr + tid);
  o.x = fmaxf(v1.x - tau, 0.0f); o.y = fmaxf(v1.y - tau, 0.0f);
  o.z = fmaxf(v1.z - tau, 0.0f); o.w = fmaxf(v1.w - tau, 0.0f);
  __builtin_nontemporal_store(o, outr + tid + THREADS);
  o.x = fmaxf(v2.x - tau, 0.0f); o.y = fmaxf(v2.y - tau, 0.0f);
  o.z = fmaxf(v2.z - tau, 0.0f); o.w = fmaxf(v2.w - tau, 0.0f);
  __builtin_nontemporal_store(o, outr + tid + 2 * THREADS);
  o.x = fmaxf(v3.x - tau, 0.0f); o.y = fmaxf(v3.y - tau, 0.0f);
  o.z = fmaxf(v3.z - tau, 0.0f); o.w = fmaxf(v3.w - tau, 0.0f);
  __builtin_nontemporal_store(o, outr + tid + 3 * THREADS);
}

extern "C" void kernel_launch(void* const* d_in, const int* in_sizes, int n_in,
                              void* d_out, int out_size, void* d_ws,
                              size_t ws_size, hipStream_t stream) {
  const float* x = (const float*)d_in[0];
  float* out = (float*)d_out;
  const int rows = in_sizes[0] / COLS;  // 8192
  sparsemax_kernel<<<rows, THREADS, 0, stream>>>(x, out);
}